// Round 1
// baseline (601.890 us; speedup 1.0000x reference)
//
#include <hip/hip_runtime.h>
#include <cstdint>
#include <cstddef>

// N=50000 nodes, E=500000 edges, EMB=64, PRED_IN=276.
// Padded-K bf16 MFMA layout (K=288 = 9*32):
//   pk   0.. 63 : q_emb     (k 0..63)
//   pk  64..127 : edge_attr (k 138..201)
//   pk 128..207 : h_e[src]  (k 64..137) + 6 pad
//   pk 208..287 : h_e[dst]  (k 202..275) + 6 pad
// h_e stored bf16 [N][80]: x(64) topic(2) f1(2) f2(2) r1(2) r2(2) pad(6).
//
// Round-3 change: k_gemm retiled from 4 M-tiles/wave (64 edges) to 2 M-tiles
// (32 edges). acc 64->32 AGPR cuts unified regs ~132->~100, lifting occupancy
// 3->5 waves/SIMD; grid 1954->3907 blocks gives ~15 blocks/CU of work.
// k_gemm was latency-bound (1.6 TB/s at 229 MB fetch == BW floor volume).

typedef __bf16 bf16x8 __attribute__((ext_vector_type(8)));
typedef float f32x4 __attribute__((ext_vector_type(4)));

__device__ __forceinline__ unsigned int f2bf1(float f) {   // RNE fp32->bf16
    unsigned int u = __float_as_uint(f);
    return (u + 0x7fffu + ((u >> 16) & 1u)) >> 16;
}
__device__ __forceinline__ unsigned int pk2(float a, float b) {
    return f2bf1(a) | (f2bf1(b) << 16);
}
__device__ __forceinline__ bf16x8 cvt8(const float* __restrict__ p) {
    float4 v0 = *(const float4*)p;
    float4 v1 = *(const float4*)(p + 4);
    bf16x8 r;
    r[0] = (__bf16)v0.x; r[1] = (__bf16)v0.y; r[2] = (__bf16)v0.z; r[3] = (__bf16)v0.w;
    r[4] = (__bf16)v1.x; r[5] = (__bf16)v1.y; r[6] = (__bf16)v1.z; r[7] = (__bf16)v1.w;
    return r;
}

// ---------------------------------------------------------------------------
// Prep
// ---------------------------------------------------------------------------

__global__ void k_detect(const int* __restrict__ idx, int E, int* __restrict__ flag) {
    int e = blockIdx.x * blockDim.x + threadIdx.x;
    bool nz = (e < E) && (idx[2 * e + 1] != 0);
    unsigned long long m = __ballot(nz);
    if (m != 0ull && (threadIdx.x & 63) == 0) atomicOr(flag, 1);
}

// unpack indices + CSR slot assignment (the only atomics in prep: 2 int/edge)
__global__ void k_convert(const int* __restrict__ idx, int E, const int* __restrict__ flag,
                          int* __restrict__ src_i, int* __restrict__ dst_i,
                          int* __restrict__ cnt_dst, int* __restrict__ cnt_src,
                          unsigned short* __restrict__ pos_f, unsigned short* __restrict__ pos_r) {
    int e = blockIdx.x * blockDim.x + threadIdx.x;
    if (e >= E) return;
    int s, d;
    if (*flag) { s = idx[e];     d = idx[E + e]; }
    else       { s = idx[2 * e]; d = idx[2 * E + 2 * e]; }
    src_i[e] = s; dst_i[e] = d;
    pos_f[e] = (unsigned short)atomicAdd(&cnt_dst[d], 1);
    pos_r[e] = (unsigned short)atomicAdd(&cnt_src[s], 1);
}

// exclusive scan of cnt -> off; block 0: cnt_dst->off_f, block 1: cnt_src->off_r
__global__ void k_scan(const int* __restrict__ cnt_dst, const int* __restrict__ cnt_src,
                       int* __restrict__ off_f, int* __restrict__ off_r, int N) {
    const int* cnt = (blockIdx.x == 0) ? cnt_dst : cnt_src;
    int* off       = (blockIdx.x == 0) ? off_f   : off_r;
    const int t = threadIdx.x;                 // 1024 threads
    const int C = (N + 1023) / 1024;
    int lo = t * C, hi = lo + C; if (hi > N) hi = N; if (lo > N) lo = N;
    int sum = 0;
    for (int i = lo; i < hi; ++i) sum += cnt[i];
    __shared__ int wsum[16];
    int lane = t & 63, wv = t >> 6;
    int v = sum;
    for (int ofs = 1; ofs < 64; ofs <<= 1) {
        int u = __shfl_up(v, ofs);
        if (lane >= ofs) v += u;
    }
    if (lane == 63) wsum[wv] = v;
    __syncthreads();
    if (wv == 0) {
        int x = (lane < 16) ? wsum[lane] : 0;
        for (int ofs = 1; ofs < 16; ofs <<= 1) {
            int u = __shfl_up(x, ofs);
            if (lane >= ofs) x += u;
        }
        if (lane < 16) wsum[lane] = x;
    }
    __syncthreads();
    int base = (wv > 0 ? wsum[wv - 1] : 0) + (v - sum);
    for (int i = lo; i < hi; ++i) { off[i] = base; base += cnt[i]; }
}

__global__ void k_fill(const int* __restrict__ src_i, const int* __restrict__ dst_i,
                       const unsigned short* __restrict__ pos_f, const unsigned short* __restrict__ pos_r,
                       const int* __restrict__ off_f, const int* __restrict__ off_r,
                       int* __restrict__ csr_f, int* __restrict__ csr_r, int E) {
    int e = blockIdx.x * blockDim.x + threadIdx.x;
    if (e >= E) return;
    int s = src_i[e], d = dst_i[e];
    csr_f[off_f[d] + pos_f[e]] = s;
    csr_r[off_r[s] + pos_r[e]] = d;
}

// atomic-free segment means (normalized at write)
// fwd/rev split across 2N threads: N-thread version left half the CUs idle
// on a latency-bound dependent-gather loop.
__global__ void k_round(const int* __restrict__ off_f, const int* __restrict__ csr_f,
                        const int* __restrict__ off_r, const int* __restrict__ csr_r,
                        const float* __restrict__ hf_in,   // gathered for forward
                        const float* __restrict__ hr_in,   // gathered for reverse
                        float* __restrict__ f_out, float* __restrict__ r_out,
                        int N, int E) {
    int gid = blockIdx.x * blockDim.x + threadIdx.x;
    if (gid >= 2 * N) return;
    const bool rev = gid >= N;
    const int n = rev ? gid - N : gid;
    const int* __restrict__ off = rev ? off_r : off_f;
    const int* __restrict__ csr = rev ? csr_r : csr_f;
    const float2* __restrict__ h = (const float2*)(rev ? hr_in : hf_in);
    float2* __restrict__ o = (float2*)(rev ? r_out : f_out);
    int b = off[n], e = (n + 1 < N) ? off[n + 1] : E;
    float sx = 0.f, sy = 0.f;
    for (int j = b; j < e; ++j) { float2 t = h[csr[j]]; sx += t.x; sy += t.y; }
    float inv = 1.0f / (float)max(e - b, 1);
    o[n] = make_float2(sx * inv, sy * inv);
}

// build bf16 h_e row (all feature buffers pre-normalized)
__global__ void k_build(const float* __restrict__ x, const float* __restrict__ topic,
                        const float* __restrict__ nte,
                        const float* __restrict__ f1, const float* __restrict__ f2,
                        const float* __restrict__ r1, const float* __restrict__ r2,
                        unsigned short* __restrict__ he, int N) {
    int n = blockIdx.x * blockDim.x + threadIdx.x;
    if (n >= N) return;
    const float4* xr = (const float4*)(x + (size_t)n * 64);
    float4 v[16];
    bool allz = true;
#pragma unroll
    for (int i = 0; i < 16; ++i) {
        v[i] = xr[i];
        allz = allz && (v[i].x == 0.f && v[i].y == 0.f && v[i].z == 0.f && v[i].w == 0.f);
    }
    const float4* nr = (const float4*)nte;
    unsigned int row[40];
#pragma unroll
    for (int i = 0; i < 16; ++i) {
        float4 s = allz ? nr[i] : v[i];
        row[2 * i]     = pk2(s.x, s.y);
        row[2 * i + 1] = pk2(s.z, s.w);
    }
    row[32] = pk2(topic[2 * n], topic[2 * n + 1]);
    row[33] = pk2(f1[2 * n], f1[2 * n + 1]);
    row[34] = pk2(f2[2 * n], f2[2 * n + 1]);
    row[35] = pk2(r1[2 * n], r1[2 * n + 1]);
    row[36] = pk2(r2[2 * n], r2[2 * n + 1]);
    row[37] = 0u; row[38] = 0u; row[39] = 0u;
    uint4* dst = (uint4*)(he + (size_t)n * 80);
#pragma unroll
    for (int i = 0; i < 10; ++i) dst[i] = ((const uint4*)row)[i];
}

// padded bf16 W1^T [64 cols][288 pk]
__global__ void k_w1t(const float* __restrict__ W1, unsigned short* __restrict__ W1T) {
    int i = blockIdx.x * blockDim.x + threadIdx.x;
    if (i >= 64 * 288) return;
    int col = i / 288, pk = i - col * 288;
    int k = 0; bool valid = true;
    if (pk < 64)       { k = pk; }
    else if (pk < 128) { k = 138 + (pk - 64); }
    else if (pk < 208) { int j = pk - 128; k = 64 + j;  valid = j < 74; }
    else               { int j = pk - 208; k = 202 + j; valid = j < 74; }
    float v = valid ? W1[k * 64 + col] : 0.f;
    W1T[col * 288 + pk] = (unsigned short)f2bf1(v);
}

// ---------------------------------------------------------------------------
// MFMA edge-MLP, LDS-free: 128 edges/block, 4 waves, 32 edges/wave (2 M-tiles).
// B frags read from L1/L2-resident W1T; he frags gathered per-lane from global.
// ks-outer loop: each B frag read once per wave.
// 2 M-tiles (vs 4) halves the accumulator file (32 AGPR) -> ~5 waves/SIMD
// occupancy to hide the random he-gather latency.
// ---------------------------------------------------------------------------

__launch_bounds__(256, 4)
__global__ void k_gemm(const float* __restrict__ q_emb,
                       const float* __restrict__ edge_attr,
                       const unsigned short* __restrict__ he,
                       const unsigned short* __restrict__ W1T,
                       const int* __restrict__ src_i, const int* __restrict__ dst_i,
                       const float* __restrict__ b1, const float* __restrict__ W2,
                       const float* __restrict__ b2, float* __restrict__ out, int E)
{
    const int tid = threadIdx.x;
    const int w = tid >> 6, l = tid & 63, c = l & 15, q = l >> 4;
    const int ebase = blockIdx.x * 128 + w * 32;

    const float* gq[2];
    const float* ga[2];
    const unsigned short* hs[2];
    const unsigned short* hd[2];
#pragma unroll
    for (int t = 0; t < 2; ++t) {
        int ee = ebase + t * 16 + c; ee = ee < E ? ee : E - 1;
        int s = src_i[ee], d = dst_i[ee];
        gq[t] = q_emb     + (size_t)ee * 64 + q * 8;
        ga[t] = edge_attr + (size_t)ee * 64 + q * 8;
        hs[t] = he + (size_t)s * 80 + q * 8;
        hd[t] = he + (size_t)d * 80 + q * 8;
    }

    float b1v[4], w2v[4];
#pragma unroll
    for (int ct = 0; ct < 4; ++ct) { b1v[ct] = b1[ct * 16 + c]; w2v[ct] = W2[ct * 16 + c]; }
    const float bb = b2[0];

    f32x4 acc[2][4] = {};   // [tile][ct]

    const unsigned short* wrow = W1T + (size_t)c * 288 + q * 8;
#define BF(ct, ks) (*(const bf16x8*)(wrow + (ct) * (16 * 288) + (ks) * 32))
#define KSTEP(ks, AEXPR)                                                               \
    {                                                                                  \
        bf16x8 bf0 = BF(0, ks), bf1 = BF(1, ks), bf2 = BF(2, ks), bf3 = BF(3, ks);     \
        _Pragma("unroll")                                                              \
        for (int t = 0; t < 2; ++t) {                                                  \
            bf16x8 a = (AEXPR);                                                        \
            acc[t][0] = __builtin_amdgcn_mfma_f32_16x16x32_bf16(a, bf0, acc[t][0], 0, 0, 0); \
            acc[t][1] = __builtin_amdgcn_mfma_f32_16x16x32_bf16(a, bf1, acc[t][1], 0, 0, 0); \
            acc[t][2] = __builtin_amdgcn_mfma_f32_16x16x32_bf16(a, bf2, acc[t][2], 0, 0, 0); \
            acc[t][3] = __builtin_amdgcn_mfma_f32_16x16x32_bf16(a, bf3, acc[t][3], 0, 0, 0); \
        }                                                                              \
    }

    KSTEP(0, cvt8(gq[t]))
    KSTEP(1, cvt8(gq[t] + 32))
    KSTEP(2, cvt8(ga[t]))
    KSTEP(3, cvt8(ga[t] + 32))
    KSTEP(4, (*(const bf16x8*)(hs[t])))
    KSTEP(5, (*(const bf16x8*)(hs[t] + 32)))
    KSTEP(6, (*(const bf16x8*)((q < 2) ? (hs[t] + 64) : (hd[t] - 16))))
    KSTEP(7, (*(const bf16x8*)(hd[t] + 16)))
    KSTEP(8, (*(const bf16x8*)(hd[t] + 48)))
#undef KSTEP
#undef BF

#pragma unroll
    for (int t = 0; t < 2; ++t) {
        float pr[4];
#pragma unroll
        for (int r = 0; r < 4; ++r) {
            float h0 = fmaxf(acc[t][0][r] + b1v[0], 0.f);
            float h1 = fmaxf(acc[t][1][r] + b1v[1], 0.f);
            float h2 = fmaxf(acc[t][2][r] + b1v[2], 0.f);
            float h3 = fmaxf(acc[t][3][r] + b1v[3], 0.f);
            float p = fmaf(h0, w2v[0], fmaf(h1, w2v[1], fmaf(h2, w2v[2], h3 * w2v[3])));
            p += __shfl_xor(p, 1);
            p += __shfl_xor(p, 2);
            p += __shfl_xor(p, 4);
            p += __shfl_xor(p, 8);
            pr[r] = p;
        }
        if (c == 0) {
            int eo = ebase + t * 16 + q * 4;     // E % 16 == 0: tile fully valid or fully out
            if (eo < E) {
                float4 o = make_float4(pr[0] + bb, pr[1] + bb, pr[2] + bb, pr[3] + bb);
                *(float4*)&out[eo] = o;
            }
        }
    }
}

// ---------------------------------------------------------------------------
// Launch
// ---------------------------------------------------------------------------

extern "C" void kernel_launch(void* const* d_in, const int* in_sizes, int n_in,
                              void* d_out, int out_size, void* d_ws, size_t ws_size,
                              hipStream_t stream)
{
    const float* x         = (const float*)d_in[0];
    const int*   eidx      = (const int*)  d_in[1];
    const float* edge_attr = (const float*)d_in[2];
    const float* topic     = (const float*)d_in[3];
    const float* q_emb     = (const float*)d_in[4];
    const float* nte       = (const float*)d_in[5];
    const float* W1        = (const float*)d_in[6];
    const float* b1        = (const float*)d_in[7];
    const float* W2        = (const float*)d_in[8];
    const float* b2        = (const float*)d_in[9];
    float* out = (float*)d_out;

    const int E = out_size;             // 500000
    const int N = in_sizes[0] / 64;     // 50000

    // Workspace (aliased; total == 14,036,880 B, same as round-2 which fit):
    // [flag 16][src_i 4E][dst_i 4E][off_f 4N][off_r 4N]
    // [fblk: f1 2N | f2 2N | r1 2N | r2 2N floats]  (cnt_dst/cnt_src alias f1's ints)
    // [heblk: max(he 160N B, pos_f 2E + pos_r 2E + csr_f 4E + csr_r 4E B)]
    // [W1T 64*288*2]
    char* ws = (char*)d_ws;
    int* flag  = (int*)ws;
    int* src_i = (int*)(ws + 16);
    int* dst_i = src_i + E;
    int* off_f = dst_i + E;
    int* off_r = off_f + N;
    float* fblk = (float*)(off_r + N);
    float* f1 = fblk;
    float* f2 = fblk + 2 * (size_t)N;
    float* r1 = fblk + 4 * (size_t)N;
    float* r2 = fblk + 6 * (size_t)N;
    int* cnt_dst = (int*)f1;            // dead before f1 is written
    int* cnt_src = cnt_dst + N;
    char* heblk = (char*)(fblk + 8 * (size_t)N);
    unsigned short* pos_f = (unsigned short*)heblk;          // dead before he is written
    unsigned short* pos_r = pos_f + E;
    int* csr_f = (int*)(pos_r + E);
    int* csr_r = csr_f + E;
    unsigned short* he = (unsigned short*)heblk;
    size_t he_bytes = (size_t)N * 160;
    size_t trans_bytes = (size_t)E * 12;
    size_t heblk_bytes = he_bytes > trans_bytes ? he_bytes : trans_bytes;
    unsigned short* W1T = (unsigned short*)(heblk + heblk_bytes);

    size_t needed = 16 + (size_t)8 * E + (size_t)8 * N + (size_t)32 * N + heblk_bytes + 64 * 288 * 2;
    if (ws_size < needed) return;

    hipMemsetAsync(flag, 0, 16, stream);
    hipMemsetAsync(cnt_dst, 0, (size_t)8 * N, stream);   // both cnt arrays

    const int gE = (E + 255) / 256;
    const int gN = (N + 255) / 256;
    const int gN2 = (2 * N + 255) / 256;

    k_detect <<<gE, 256, 0, stream>>>(eidx, E, flag);
    k_convert<<<gE, 256, 0, stream>>>(eidx, E, flag, src_i, dst_i,
                                      cnt_dst, cnt_src, pos_f, pos_r);
    k_scan   <<<2, 1024, 0, stream>>>(cnt_dst, cnt_src, off_f, off_r, N);
    k_fill   <<<gE, 256, 0, stream>>>(src_i, dst_i, pos_f, pos_r, off_f, off_r,
                                      csr_f, csr_r, E);
    k_round  <<<gN2, 256, 0, stream>>>(off_f, csr_f, off_r, csr_r, topic, topic, f1, r1, N, E);
    k_round  <<<gN2, 256, 0, stream>>>(off_f, csr_f, off_r, csr_r, f1, r1, f2, r2, N, E);
    k_build  <<<gN, 256, 0, stream>>>(x, topic, nte, f1, f2, r1, r2, he, N);
    k_w1t    <<<(64 * 288 + 255) / 256, 256, 0, stream>>>(W1, W1T);

    k_gemm<<<(E + 127) / 128, 256, 0, stream>>>(q_emb, edge_attr, he, W1T,
                                                src_i, dst_i, b1, W2, b2, out, E);
}

// Round 2
// 559.133 us; speedup vs baseline: 1.0765x; 1.0765x over previous
//
#include <hip/hip_runtime.h>
#include <cstdint>
#include <cstddef>

// N=50000 nodes, E=500000 edges, EMB=64, PRED_IN=276.
// Padded-K bf16 MFMA layout (K=288 = 9*32):
//   pk   0.. 63 : q_emb     (k 0..63)
//   pk  64..127 : edge_attr (k 138..201)
//   pk 128..207 : h_e[src]  (k 64..137) + 6 pad
//   pk 208..287 : h_e[dst]  (k 202..275) + 6 pad
// h_e stored bf16 [N][80]: x(64) topic(2) f1(2) f2(2) r1(2) r2(2) pad(6).
//
// Round-4: k_gemm rebuilt as an async pipeline (was MLP-bound at 1.6 TB/s:
// per-wave in-flight bytes * waves / latency == measured BW; occupancy change
// R1 proved occupancy is not the lever).
//  - W1T staged to LDS once  -> B-frags are ds_read (lgkm), not vmcnt
//  - he[src/dst] gathered via global_load_lds (zero-VGPR async DMA)
//  - q/ea double-buffered in registers (2-deep)
//  - steady loop: s_waitcnt vmcnt(15) only; no vmcnt(0), no barrier

typedef __bf16 bf16x8 __attribute__((ext_vector_type(8)));
typedef float f32x4 __attribute__((ext_vector_type(4)));

__device__ __forceinline__ unsigned int f2bf1(float f) {   // RNE fp32->bf16
    unsigned int u = __float_as_uint(f);
    return (u + 0x7fffu + ((u >> 16) & 1u)) >> 16;
}
__device__ __forceinline__ unsigned int pk2(float a, float b) {
    return f2bf1(a) | (f2bf1(b) << 16);
}
__device__ __forceinline__ bf16x8 cvt8v(float4 a, float4 b) {
    bf16x8 r;
    r[0] = (__bf16)a.x; r[1] = (__bf16)a.y; r[2] = (__bf16)a.z; r[3] = (__bf16)a.w;
    r[4] = (__bf16)b.x; r[5] = (__bf16)b.y; r[6] = (__bf16)b.z; r[7] = (__bf16)b.w;
    return r;
}

#define GL16(gp, lp)                                                        \
    __builtin_amdgcn_global_load_lds(                                       \
        (const __attribute__((address_space(1))) void*)(gp),                \
        (__attribute__((address_space(3))) void*)(lp), 16, 0, 0)

// ---------------------------------------------------------------------------
// Prep (unchanged)
// ---------------------------------------------------------------------------

__global__ void k_detect(const int* __restrict__ idx, int E, int* __restrict__ flag) {
    int e = blockIdx.x * blockDim.x + threadIdx.x;
    bool nz = (e < E) && (idx[2 * e + 1] != 0);
    unsigned long long m = __ballot(nz);
    if (m != 0ull && (threadIdx.x & 63) == 0) atomicOr(flag, 1);
}

__global__ void k_convert(const int* __restrict__ idx, int E, const int* __restrict__ flag,
                          int* __restrict__ src_i, int* __restrict__ dst_i,
                          int* __restrict__ cnt_dst, int* __restrict__ cnt_src,
                          unsigned short* __restrict__ pos_f, unsigned short* __restrict__ pos_r) {
    int e = blockIdx.x * blockDim.x + threadIdx.x;
    if (e >= E) return;
    int s, d;
    if (*flag) { s = idx[e];     d = idx[E + e]; }
    else       { s = idx[2 * e]; d = idx[2 * E + 2 * e]; }
    src_i[e] = s; dst_i[e] = d;
    pos_f[e] = (unsigned short)atomicAdd(&cnt_dst[d], 1);
    pos_r[e] = (unsigned short)atomicAdd(&cnt_src[s], 1);
}

__global__ void k_scan(const int* __restrict__ cnt_dst, const int* __restrict__ cnt_src,
                       int* __restrict__ off_f, int* __restrict__ off_r, int N) {
    const int* cnt = (blockIdx.x == 0) ? cnt_dst : cnt_src;
    int* off       = (blockIdx.x == 0) ? off_f   : off_r;
    const int t = threadIdx.x;                 // 1024 threads
    const int C = (N + 1023) / 1024;
    int lo = t * C, hi = lo + C; if (hi > N) hi = N; if (lo > N) lo = N;
    int sum = 0;
    for (int i = lo; i < hi; ++i) sum += cnt[i];
    __shared__ int wsum[16];
    int lane = t & 63, wv = t >> 6;
    int v = sum;
    for (int ofs = 1; ofs < 64; ofs <<= 1) {
        int u = __shfl_up(v, ofs);
        if (lane >= ofs) v += u;
    }
    if (lane == 63) wsum[wv] = v;
    __syncthreads();
    if (wv == 0) {
        int x = (lane < 16) ? wsum[lane] : 0;
        for (int ofs = 1; ofs < 16; ofs <<= 1) {
            int u = __shfl_up(x, ofs);
            if (lane >= ofs) x += u;
        }
        if (lane < 16) wsum[lane] = x;
    }
    __syncthreads();
    int base = (wv > 0 ? wsum[wv - 1] : 0) + (v - sum);
    for (int i = lo; i < hi; ++i) { off[i] = base; base += cnt[i]; }
}

__global__ void k_fill(const int* __restrict__ src_i, const int* __restrict__ dst_i,
                       const unsigned short* __restrict__ pos_f, const unsigned short* __restrict__ pos_r,
                       const int* __restrict__ off_f, const int* __restrict__ off_r,
                       int* __restrict__ csr_f, int* __restrict__ csr_r, int E) {
    int e = blockIdx.x * blockDim.x + threadIdx.x;
    if (e >= E) return;
    int s = src_i[e], d = dst_i[e];
    csr_f[off_f[d] + pos_f[e]] = s;
    csr_r[off_r[s] + pos_r[e]] = d;
}

__global__ void k_round(const int* __restrict__ off_f, const int* __restrict__ csr_f,
                        const int* __restrict__ off_r, const int* __restrict__ csr_r,
                        const float* __restrict__ hf_in,
                        const float* __restrict__ hr_in,
                        float* __restrict__ f_out, float* __restrict__ r_out,
                        int N, int E) {
    int gid = blockIdx.x * blockDim.x + threadIdx.x;
    if (gid >= 2 * N) return;
    const bool rev = gid >= N;
    const int n = rev ? gid - N : gid;
    const int* __restrict__ off = rev ? off_r : off_f;
    const int* __restrict__ csr = rev ? csr_r : csr_f;
    const float2* __restrict__ h = (const float2*)(rev ? hr_in : hf_in);
    float2* __restrict__ o = (float2*)(rev ? r_out : f_out);
    int b = off[n], e = (n + 1 < N) ? off[n + 1] : E;
    float sx = 0.f, sy = 0.f;
    for (int j = b; j < e; ++j) { float2 t = h[csr[j]]; sx += t.x; sy += t.y; }
    float inv = 1.0f / (float)max(e - b, 1);
    o[n] = make_float2(sx * inv, sy * inv);
}

__global__ void k_build(const float* __restrict__ x, const float* __restrict__ topic,
                        const float* __restrict__ nte,
                        const float* __restrict__ f1, const float* __restrict__ f2,
                        const float* __restrict__ r1, const float* __restrict__ r2,
                        unsigned short* __restrict__ he, int N) {
    int n = blockIdx.x * blockDim.x + threadIdx.x;
    if (n >= N) return;
    const float4* xr = (const float4*)(x + (size_t)n * 64);
    float4 v[16];
    bool allz = true;
#pragma unroll
    for (int i = 0; i < 16; ++i) {
        v[i] = xr[i];
        allz = allz && (v[i].x == 0.f && v[i].y == 0.f && v[i].z == 0.f && v[i].w == 0.f);
    }
    const float4* nr = (const float4*)nte;
    unsigned int row[40];
#pragma unroll
    for (int i = 0; i < 16; ++i) {
        float4 s = allz ? nr[i] : v[i];
        row[2 * i]     = pk2(s.x, s.y);
        row[2 * i + 1] = pk2(s.z, s.w);
    }
    row[32] = pk2(topic[2 * n], topic[2 * n + 1]);
    row[33] = pk2(f1[2 * n], f1[2 * n + 1]);
    row[34] = pk2(f2[2 * n], f2[2 * n + 1]);
    row[35] = pk2(r1[2 * n], r1[2 * n + 1]);
    row[36] = pk2(r2[2 * n], r2[2 * n + 1]);
    row[37] = 0u; row[38] = 0u; row[39] = 0u;
    uint4* dst = (uint4*)(he + (size_t)n * 80);
#pragma unroll
    for (int i = 0; i < 10; ++i) dst[i] = ((const uint4*)row)[i];
}

__global__ void k_w1t(const float* __restrict__ W1, unsigned short* __restrict__ W1T) {
    int i = blockIdx.x * blockDim.x + threadIdx.x;
    if (i >= 64 * 288) return;
    int col = i / 288, pk = i - col * 288;
    int k = 0; bool valid = true;
    if (pk < 64)       { k = pk; }
    else if (pk < 128) { k = 138 + (pk - 64); }
    else if (pk < 208) { int j = pk - 128; k = 64 + j;  valid = j < 74; }
    else               { int j = pk - 208; k = 202 + j; valid = j < 74; }
    float v = valid ? W1[k * 64 + col] : 0.f;
    W1T[col * 288 + pk] = (unsigned short)f2bf1(v);
}

// ---------------------------------------------------------------------------
// MFMA edge-MLP, async pipeline.
// 128 threads = 2 waves/block, 16 edges (1 M-tile) per wave per iteration.
// LDS 57,344 B/block: [W1T 36,864][wave0 buf0/buf1 5,120 each][wave1 ...].
// he buffers: chunk-plane layout, plane p (0..19) at p*256 + edge*16:
//   planes 0..9 = he[src] chunks, planes 10..19 = he[dst] chunks.
// Steady loop per wave (no barriers, no vmcnt(0)):
//   issue 8 q/ea reg loads (T+NW) + 5 global_load_lds (T+NW) + 2 idx loads
//   s_waitcnt vmcnt(15)   // all older (tile T's data) complete
//   compute tile T: ds_read B/A frags + 36 MFMA + reduce + store
// ---------------------------------------------------------------------------

__launch_bounds__(128, 2)
__global__ void k_gemm(const float* __restrict__ q_emb,
                       const float* __restrict__ edge_attr,
                       const unsigned short* __restrict__ he,
                       const unsigned short* __restrict__ W1Tg,
                       const int* __restrict__ src_i, const int* __restrict__ dst_i,
                       const float* __restrict__ b1, const float* __restrict__ W2,
                       const float* __restrict__ b2, float* __restrict__ out, int E)
{
    __shared__ __align__(64) char smem[57344];
    const int tid = threadIdx.x;
    const int w = tid >> 6, l = tid & 63, c = l & 15, q = l >> 4;
    const int NW = gridDim.x * 2;
    const int gw = blockIdx.x * 2 + w;
    const int ntiles = E / 16;          // E % 16 == 0

    // W1T -> LDS (36 KB, linear copy; 36 x 1KB DMA, split across 2 waves)
#pragma unroll
    for (int jj = 0; jj < 18; ++jj) {
        int j = w * 18 + jj;
        GL16((const char*)W1Tg + j * 1024 + l * 16, smem + j * 1024);
    }

    char* buf0 = smem + 36864 + (w * 2) * 5120;
    char* buf1 = buf0 + 5120;

    int T = gw;
    // prologue: stage tile T into buf0, prefetch q/ea(T) regs, idx(T+NW)
    {
        int e0 = T * 16 + (l & 15);
        int s0 = src_i[e0], d0 = dst_i[e0];
#pragma unroll
        for (int j = 0; j < 5; ++j) {
            int ch = j * 4 + (l >> 4);
            int node = ch < 10 ? s0 : d0;
            int chunk = ch < 10 ? ch : ch - 10;
            GL16((const char*)he + (size_t)node * 160 + chunk * 16, buf0 + j * 1024);
        }
    }
    const float* qr0 = q_emb     + (size_t)(T * 16 + c) * 64 + q * 8;
    const float* ar0 = edge_attr + (size_t)(T * 16 + c) * 64 + q * 8;
    float4 qc0 = *(const float4*)qr0,        qc1 = *(const float4*)(qr0 + 4);
    float4 qc2 = *(const float4*)(qr0 + 32), qc3 = *(const float4*)(qr0 + 36);
    float4 ec0 = *(const float4*)ar0,        ec1 = *(const float4*)(ar0 + 4);
    float4 ec2 = *(const float4*)(ar0 + 32), ec3 = *(const float4*)(ar0 + 36);
    int si_n, di_n;
    {
        int en = min(T + NW, ntiles - 1) * 16 + (l & 15);
        si_n = src_i[en]; di_n = dst_i[en];
    }
    float b1v[4], w2v[4];
#pragma unroll
    for (int ct = 0; ct < 4; ++ct) { b1v[ct] = b1[ct * 16 + c]; w2v[ct] = W2[ct * 16 + c]; }
    const float bb = b2[0];
    __syncthreads();   // drains all prologue DMA + makes W1T visible to both waves

    int cur = 0;
    while (T < ntiles) {
        const int Tn = T + NW;
        const bool more = Tn < ntiles;
        float4 qn0, qn1, qn2, qn3, en0, en1, en2, en3;
        int si_f = si_n, di_f = di_n;
        char* sbuf = cur ? buf0 : buf1;   // staging target
        char* cbuf = cur ? buf1 : buf0;   // compute source

        if (more) {
            const float* qr = q_emb     + (size_t)(Tn * 16 + c) * 64 + q * 8;
            const float* ar = edge_attr + (size_t)(Tn * 16 + c) * 64 + q * 8;
            qn0 = *(const float4*)qr;        qn1 = *(const float4*)(qr + 4);
            qn2 = *(const float4*)(qr + 32); qn3 = *(const float4*)(qr + 36);
            en0 = *(const float4*)ar;        en1 = *(const float4*)(ar + 4);
            en2 = *(const float4*)(ar + 32); en3 = *(const float4*)(ar + 36);
#pragma unroll
            for (int j = 0; j < 5; ++j) {
                int ch = j * 4 + (l >> 4);
                int node = ch < 10 ? si_n : di_n;
                int chunk = ch < 10 ? ch : ch - 10;
                GL16((const char*)he + (size_t)node * 160 + chunk * 16, sbuf + j * 1024);
            }
            int ef = min(Tn + NW, ntiles - 1) * 16 + (l & 15);
            si_f = src_i[ef]; di_f = dst_i[ef];
            asm volatile("s_waitcnt vmcnt(15)" ::: "memory");
        } else {
            qn0 = qc0; qn1 = qc1; qn2 = qc2; qn3 = qc3;
            en0 = ec0; en1 = ec1; en2 = ec2; en3 = ec3;
            asm volatile("s_waitcnt vmcnt(0)" ::: "memory");
        }
        __builtin_amdgcn_sched_barrier(0);

        // ---- compute tile T ----
        f32x4 acc0 = {}, acc1 = {}, acc2 = {}, acc3 = {};
        const char* wrow = smem + c * 576 + q * 16;
#define BF(ct, ks) (*(const bf16x8*)(wrow + (ct) * 9216 + (ks) * 64))
#define HEF(pl) (*(const bf16x8*)(cbuf + (pl) * 256 + c * 16))
#define KST(ks, A)                                                                 \
        {                                                                          \
            bf16x8 a_ = (A);                                                       \
            acc0 = __builtin_amdgcn_mfma_f32_16x16x32_bf16(a_, BF(0, ks), acc0, 0, 0, 0); \
            acc1 = __builtin_amdgcn_mfma_f32_16x16x32_bf16(a_, BF(1, ks), acc1, 0, 0, 0); \
            acc2 = __builtin_amdgcn_mfma_f32_16x16x32_bf16(a_, BF(2, ks), acc2, 0, 0, 0); \
            acc3 = __builtin_amdgcn_mfma_f32_16x16x32_bf16(a_, BF(3, ks), acc3, 0, 0, 0); \
        }
        KST(0, cvt8v(qc0, qc1))
        KST(1, cvt8v(qc2, qc3))
        KST(2, cvt8v(ec0, ec1))
        KST(3, cvt8v(ec2, ec3))
        KST(4, HEF(q))            // hs chunks q
        KST(5, HEF(q + 4))        // hs chunks q+4
        KST(6, HEF(q + 8))        // q<2: hs 8,9 ; q>=2: hd 0,1 (planes contiguous)
        KST(7, HEF(q + 12))       // hd chunks q+2
        KST(8, HEF(q + 16))       // hd chunks q+6
#undef KST
#undef HEF
#undef BF

        float pr[4];
#pragma unroll
        for (int r = 0; r < 4; ++r) {
            float h0 = fmaxf(acc0[r] + b1v[0], 0.f);
            float h1 = fmaxf(acc1[r] + b1v[1], 0.f);
            float h2 = fmaxf(acc2[r] + b1v[2], 0.f);
            float h3 = fmaxf(acc3[r] + b1v[3], 0.f);
            float p = fmaf(h0, w2v[0], fmaf(h1, w2v[1], fmaf(h2, w2v[2], h3 * w2v[3])));
            p += __shfl_xor(p, 1);
            p += __shfl_xor(p, 2);
            p += __shfl_xor(p, 4);
            p += __shfl_xor(p, 8);
            pr[r] = p;
        }
        if (c == 0) {
            *(float4*)&out[T * 16 + q * 4] =
                make_float4(pr[0] + bb, pr[1] + bb, pr[2] + bb, pr[3] + bb);
        }

        qc0 = qn0; qc1 = qn1; qc2 = qn2; qc3 = qn3;
        ec0 = en0; ec1 = en1; ec2 = en2; ec3 = en3;
        si_n = si_f; di_n = di_f;
        T = Tn; cur ^= 1;
    }
}

// ---------------------------------------------------------------------------
// Launch
// ---------------------------------------------------------------------------

extern "C" void kernel_launch(void* const* d_in, const int* in_sizes, int n_in,
                              void* d_out, int out_size, void* d_ws, size_t ws_size,
                              hipStream_t stream)
{
    const float* x         = (const float*)d_in[0];
    const int*   eidx      = (const int*)  d_in[1];
    const float* edge_attr = (const float*)d_in[2];
    const float* topic     = (const float*)d_in[3];
    const float* q_emb     = (const float*)d_in[4];
    const float* nte       = (const float*)d_in[5];
    const float* W1        = (const float*)d_in[6];
    const float* b1        = (const float*)d_in[7];
    const float* W2        = (const float*)d_in[8];
    const float* b2        = (const float*)d_in[9];
    float* out = (float*)d_out;

    const int E = out_size;             // 500000
    const int N = in_sizes[0] / 64;     // 50000

    char* ws = (char*)d_ws;
    int* flag  = (int*)ws;
    int* src_i = (int*)(ws + 16);
    int* dst_i = src_i + E;
    int* off_f = dst_i + E;
    int* off_r = off_f + N;
    float* fblk = (float*)(off_r + N);
    float* f1 = fblk;
    float* f2 = fblk + 2 * (size_t)N;
    float* r1 = fblk + 4 * (size_t)N;
    float* r2 = fblk + 6 * (size_t)N;
    int* cnt_dst = (int*)f1;            // dead before f1 is written
    int* cnt_src = cnt_dst + N;
    char* heblk = (char*)(fblk + 8 * (size_t)N);
    unsigned short* pos_f = (unsigned short*)heblk;          // dead before he is written
    unsigned short* pos_r = pos_f + E;
    int* csr_f = (int*)(pos_r + E);
    int* csr_r = csr_f + E;
    unsigned short* he = (unsigned short*)heblk;
    size_t he_bytes = (size_t)N * 160;
    size_t trans_bytes = (size_t)E * 12;
    size_t heblk_bytes = he_bytes > trans_bytes ? he_bytes : trans_bytes;
    unsigned short* W1T = (unsigned short*)(heblk + heblk_bytes);

    size_t needed = 16 + (size_t)8 * E + (size_t)8 * N + (size_t)32 * N + heblk_bytes + 64 * 288 * 2;
    if (ws_size < needed) return;

    hipMemsetAsync(flag, 0, 16, stream);
    hipMemsetAsync(cnt_dst, 0, (size_t)8 * N, stream);   // both cnt arrays

    const int gE = (E + 255) / 256;
    const int gN = (N + 255) / 256;
    const int gN2 = (2 * N + 255) / 256;

    k_detect <<<gE, 256, 0, stream>>>(eidx, E, flag);
    k_convert<<<gE, 256, 0, stream>>>(eidx, E, flag, src_i, dst_i,
                                      cnt_dst, cnt_src, pos_f, pos_r);
    k_scan   <<<2, 1024, 0, stream>>>(cnt_dst, cnt_src, off_f, off_r, N);
    k_fill   <<<gE, 256, 0, stream>>>(src_i, dst_i, pos_f, pos_r, off_f, off_r,
                                      csr_f, csr_r, E);
    k_round  <<<gN2, 256, 0, stream>>>(off_f, csr_f, off_r, csr_r, topic, topic, f1, r1, N, E);
    k_round  <<<gN2, 256, 0, stream>>>(off_f, csr_f, off_r, csr_r, f1, r1, f2, r2, N, E);
    k_build  <<<gN, 256, 0, stream>>>(x, topic, nte, f1, f2, r1, r2, he, N);
    k_w1t    <<<(64 * 288 + 255) / 256, 256, 0, stream>>>(W1, W1T);

    k_gemm<<<512, 128, 0, stream>>>(q_emb, edge_attr, he, W1T,
                                    src_i, dst_i, b1, W2, b2, out, E);
}

// Round 3
// 554.835 us; speedup vs baseline: 1.0848x; 1.0077x over previous
//
#include <hip/hip_runtime.h>
#include <cstdint>
#include <cstddef>

// N=50000 nodes, E=500000 edges, EMB=64, PRED_IN=276.
// Padded-K bf16 MFMA layout (K=288 = 9*32):
//   pk   0.. 63 : q_emb     (k 0..63)
//   pk  64..127 : edge_attr (k 138..201)
//   pk 128..207 : h_e[src]  (k 64..137) + 6 pad
//   pk 208..287 : h_e[dst]  (k 202..275) + 6 pad
// h_e stored bf16 [N][80]: x(64) topic(2) f1(2) f2(2) r1(2) r2(2) pad(6).
//
// Round-5 (R2 post-mortem: 107us, occ 10.6% = 1 wave/SIMD, 4.5M LDS conflicts):
//  - W1T relayout [ct][ks][lane*16] -> lane l reads l*16: conflict-free b128
//  - 256-thr blocks (4 waves), LDS 77,824 -> 2 blocks/CU = 2 waves/SIMD
//  - CSR idx prefetch depth 2 -> DMA addresses always 1 full iter old
//  - steady loop unchanged: issue 15 loads, s_waitcnt vmcnt(15), no barrier

typedef __bf16 bf16x8 __attribute__((ext_vector_type(8)));
typedef float f32x4 __attribute__((ext_vector_type(4)));

__device__ __forceinline__ unsigned int f2bf1(float f) {   // RNE fp32->bf16
    unsigned int u = __float_as_uint(f);
    return (u + 0x7fffu + ((u >> 16) & 1u)) >> 16;
}
__device__ __forceinline__ unsigned int pk2(float a, float b) {
    return f2bf1(a) | (f2bf1(b) << 16);
}
__device__ __forceinline__ bf16x8 cvt8v(float4 a, float4 b) {
    bf16x8 r;
    r[0] = (__bf16)a.x; r[1] = (__bf16)a.y; r[2] = (__bf16)a.z; r[3] = (__bf16)a.w;
    r[4] = (__bf16)b.x; r[5] = (__bf16)b.y; r[6] = (__bf16)b.z; r[7] = (__bf16)b.w;
    return r;
}

#define GL16(gp, lp)                                                        \
    __builtin_amdgcn_global_load_lds(                                       \
        (const __attribute__((address_space(1))) void*)(gp),                \
        (__attribute__((address_space(3))) void*)(lp), 16, 0, 0)

// ---------------------------------------------------------------------------
// Prep (unchanged except k_w1t layout)
// ---------------------------------------------------------------------------

__global__ void k_detect(const int* __restrict__ idx, int E, int* __restrict__ flag) {
    int e = blockIdx.x * blockDim.x + threadIdx.x;
    bool nz = (e < E) && (idx[2 * e + 1] != 0);
    unsigned long long m = __ballot(nz);
    if (m != 0ull && (threadIdx.x & 63) == 0) atomicOr(flag, 1);
}

__global__ void k_convert(const int* __restrict__ idx, int E, const int* __restrict__ flag,
                          int* __restrict__ src_i, int* __restrict__ dst_i,
                          int* __restrict__ cnt_dst, int* __restrict__ cnt_src,
                          unsigned short* __restrict__ pos_f, unsigned short* __restrict__ pos_r) {
    int e = blockIdx.x * blockDim.x + threadIdx.x;
    if (e >= E) return;
    int s, d;
    if (*flag) { s = idx[e];     d = idx[E + e]; }
    else       { s = idx[2 * e]; d = idx[2 * E + 2 * e]; }
    src_i[e] = s; dst_i[e] = d;
    pos_f[e] = (unsigned short)atomicAdd(&cnt_dst[d], 1);
    pos_r[e] = (unsigned short)atomicAdd(&cnt_src[s], 1);
}

__global__ void k_scan(const int* __restrict__ cnt_dst, const int* __restrict__ cnt_src,
                       int* __restrict__ off_f, int* __restrict__ off_r, int N) {
    const int* cnt = (blockIdx.x == 0) ? cnt_dst : cnt_src;
    int* off       = (blockIdx.x == 0) ? off_f   : off_r;
    const int t = threadIdx.x;                 // 1024 threads
    const int C = (N + 1023) / 1024;
    int lo = t * C, hi = lo + C; if (hi > N) hi = N; if (lo > N) lo = N;
    int sum = 0;
    for (int i = lo; i < hi; ++i) sum += cnt[i];
    __shared__ int wsum[16];
    int lane = t & 63, wv = t >> 6;
    int v = sum;
    for (int ofs = 1; ofs < 64; ofs <<= 1) {
        int u = __shfl_up(v, ofs);
        if (lane >= ofs) v += u;
    }
    if (lane == 63) wsum[wv] = v;
    __syncthreads();
    if (wv == 0) {
        int x = (lane < 16) ? wsum[lane] : 0;
        for (int ofs = 1; ofs < 16; ofs <<= 1) {
            int u = __shfl_up(x, ofs);
            if (lane >= ofs) x += u;
        }
        if (lane < 16) wsum[lane] = x;
    }
    __syncthreads();
    int base = (wv > 0 ? wsum[wv - 1] : 0) + (v - sum);
    for (int i = lo; i < hi; ++i) { off[i] = base; base += cnt[i]; }
}

__global__ void k_fill(const int* __restrict__ src_i, const int* __restrict__ dst_i,
                       const unsigned short* __restrict__ pos_f, const unsigned short* __restrict__ pos_r,
                       const int* __restrict__ off_f, const int* __restrict__ off_r,
                       int* __restrict__ csr_f, int* __restrict__ csr_r, int E) {
    int e = blockIdx.x * blockDim.x + threadIdx.x;
    if (e >= E) return;
    int s = src_i[e], d = dst_i[e];
    csr_f[off_f[d] + pos_f[e]] = s;
    csr_r[off_r[s] + pos_r[e]] = d;
}

__global__ void k_round(const int* __restrict__ off_f, const int* __restrict__ csr_f,
                        const int* __restrict__ off_r, const int* __restrict__ csr_r,
                        const float* __restrict__ hf_in,
                        const float* __restrict__ hr_in,
                        float* __restrict__ f_out, float* __restrict__ r_out,
                        int N, int E) {
    int gid = blockIdx.x * blockDim.x + threadIdx.x;
    if (gid >= 2 * N) return;
    const bool rev = gid >= N;
    const int n = rev ? gid - N : gid;
    const int* __restrict__ off = rev ? off_r : off_f;
    const int* __restrict__ csr = rev ? csr_r : csr_f;
    const float2* __restrict__ h = (const float2*)(rev ? hr_in : hf_in);
    float2* __restrict__ o = (float2*)(rev ? r_out : f_out);
    int b = off[n], e = (n + 1 < N) ? off[n + 1] : E;
    float sx = 0.f, sy = 0.f;
    for (int j = b; j < e; ++j) { float2 t = h[csr[j]]; sx += t.x; sy += t.y; }
    float inv = 1.0f / (float)max(e - b, 1);
    o[n] = make_float2(sx * inv, sy * inv);
}

__global__ void k_build(const float* __restrict__ x, const float* __restrict__ topic,
                        const float* __restrict__ nte,
                        const float* __restrict__ f1, const float* __restrict__ f2,
                        const float* __restrict__ r1, const float* __restrict__ r2,
                        unsigned short* __restrict__ he, int N) {
    int n = blockIdx.x * blockDim.x + threadIdx.x;
    if (n >= N) return;
    const float4* xr = (const float4*)(x + (size_t)n * 64);
    float4 v[16];
    bool allz = true;
#pragma unroll
    for (int i = 0; i < 16; ++i) {
        v[i] = xr[i];
        allz = allz && (v[i].x == 0.f && v[i].y == 0.f && v[i].z == 0.f && v[i].w == 0.f);
    }
    const float4* nr = (const float4*)nte;
    unsigned int row[40];
#pragma unroll
    for (int i = 0; i < 16; ++i) {
        float4 s = allz ? nr[i] : v[i];
        row[2 * i]     = pk2(s.x, s.y);
        row[2 * i + 1] = pk2(s.z, s.w);
    }
    row[32] = pk2(topic[2 * n], topic[2 * n + 1]);
    row[33] = pk2(f1[2 * n], f1[2 * n + 1]);
    row[34] = pk2(f2[2 * n], f2[2 * n + 1]);
    row[35] = pk2(r1[2 * n], r1[2 * n + 1]);
    row[36] = pk2(r2[2 * n], r2[2 * n + 1]);
    row[37] = 0u; row[38] = 0u; row[39] = 0u;
    uint4* dst = (uint4*)(he + (size_t)n * 80);
#pragma unroll
    for (int i = 0; i < 10; ++i) dst[i] = ((const uint4*)row)[i];
}

// W1T linear-LDS layout: ushort index i = ((ct*9 + ks)*64 + l)*8 + j
// holds W1[pk-mapped k][col] for col = ct*16 + (l&15), pk = ks*32 + (l>>4)*8 + j.
// After the identity (linear) DMA into LDS, lane l's b128 read for (ct,ks)
// sits at byte ct*9216 + ks*1024 + l*16 -> conflict-free.
__global__ void k_w1t(const float* __restrict__ W1, unsigned short* __restrict__ W1T) {
    int i = blockIdx.x * blockDim.x + threadIdx.x;
    if (i >= 64 * 288) return;
    int j = i & 7;
    int l = (i >> 3) & 63;
    int t36 = i >> 9;              // ct*9 + ks
    int ks = t36 % 9, ct = t36 / 9;
    int col = ct * 16 + (l & 15);
    int pk = ks * 32 + (l >> 4) * 8 + j;
    int k = 0; bool valid = true;
    if (pk < 64)       { k = pk; }
    else if (pk < 128) { k = 138 + (pk - 64); }
    else if (pk < 208) { int jj = pk - 128; k = 64 + jj;  valid = jj < 74; }
    else               { int jj = pk - 208; k = 202 + jj; valid = jj < 74; }
    float v = valid ? W1[k * 64 + col] : 0.f;
    W1T[i] = (unsigned short)f2bf1(v);
}

// ---------------------------------------------------------------------------
// MFMA edge-MLP, async pipeline.
// 256 threads = 4 waves/block, 16 edges (1 M-tile) per wave per iteration.
// LDS 77,824 B/block: [W1T 36,864][wave w: buf0/buf1 5,120 each at 36864+w*10240]
//   -> 2 blocks/CU -> 8 waves/CU = 2 waves/SIMD.
// he buffers: chunk-plane layout, plane p (0..19) at p*256 + edge*16:
//   planes 0..9 = he[src] chunks, planes 10..19 = he[dst] chunks.
// Steady loop per wave (no barriers, no vmcnt(0)):
//   issue 8 q/ea reg loads (T+NW) + 5 global_load_lds (T+NW, addrs from siA
//   loaded 2 iters ago) + 2 idx loads (T+3NW)
//   s_waitcnt vmcnt(15)   // all older (tile T's data) complete
//   compute tile T: linear ds_read B/A frags + 36 MFMA + reduce + store
// ---------------------------------------------------------------------------

__launch_bounds__(256, 2)
__global__ void k_gemm(const float* __restrict__ q_emb,
                       const float* __restrict__ edge_attr,
                       const unsigned short* __restrict__ he,
                       const unsigned short* __restrict__ W1Tg,
                       const int* __restrict__ src_i, const int* __restrict__ dst_i,
                       const float* __restrict__ b1, const float* __restrict__ W2,
                       const float* __restrict__ b2, float* __restrict__ out, int E)
{
    __shared__ __align__(64) char smem[77824];
    const int tid = threadIdx.x;
    const int w = tid >> 6, l = tid & 63, c = l & 15, q = l >> 4;
    const int NW = gridDim.x * 4;
    const int gw = blockIdx.x * 4 + w;
    const int ntiles = E / 16;          // E % 16 == 0

    // W1T -> LDS (36 KB linear copy; 36 x 1KB DMA, 9 per wave)
#pragma unroll
    for (int jj = 0; jj < 9; ++jj) {
        int j = w * 9 + jj;
        GL16((const char*)W1Tg + j * 1024 + l * 16, smem + j * 1024);
    }

    char* buf0 = smem + 36864 + w * 10240;
    char* buf1 = buf0 + 5120;

    int T = gw;
    // prologue: stage tile T into buf0, prefetch q/ea(T) regs, idx depth-2
    {
        int e0 = T * 16 + c;
        int s0 = src_i[e0], d0 = dst_i[e0];
#pragma unroll
        for (int j = 0; j < 5; ++j) {
            int ch = j * 4 + q;
            int node = ch < 10 ? s0 : d0;
            int chunk = ch < 10 ? ch : ch - 10;
            GL16((const char*)he + (size_t)node * 160 + chunk * 16, buf0 + j * 1024);
        }
    }
    const float* qr0 = q_emb     + (size_t)(T * 16 + c) * 64 + q * 8;
    const float* ar0 = edge_attr + (size_t)(T * 16 + c) * 64 + q * 8;
    float4 qc0 = *(const float4*)qr0,        qc1 = *(const float4*)(qr0 + 4);
    float4 qc2 = *(const float4*)(qr0 + 32), qc3 = *(const float4*)(qr0 + 36);
    float4 ec0 = *(const float4*)ar0,        ec1 = *(const float4*)(ar0 + 4);
    float4 ec2 = *(const float4*)(ar0 + 32), ec3 = *(const float4*)(ar0 + 36);
    int siA, diA, siB, diB;
    {
        int eA = min(T + NW, ntiles - 1) * 16 + c;
        int eB = min(T + 2 * NW, ntiles - 1) * 16 + c;
        siA = src_i[eA]; diA = dst_i[eA];
        siB = src_i[eB]; diB = dst_i[eB];
    }
    float b1v[4], w2v[4];
#pragma unroll
    for (int ct = 0; ct < 4; ++ct) { b1v[ct] = b1[ct * 16 + c]; w2v[ct] = W2[ct * 16 + c]; }
    const float bb = b2[0];
    __syncthreads();   // drains all prologue DMA + makes W1T visible to all waves

    int cur = 0;
    while (T < ntiles) {
        const int Tn = T + NW;
        const bool more = Tn < ntiles;
        float4 qn0, qn1, qn2, qn3, en0, en1, en2, en3;
        int siC = siB, diC = diB;
        char* sbuf = cur ? buf0 : buf1;   // staging target
        char* cbuf = cur ? buf1 : buf0;   // compute source

        if (more) {
            const float* qr = q_emb     + (size_t)(Tn * 16 + c) * 64 + q * 8;
            const float* ar = edge_attr + (size_t)(Tn * 16 + c) * 64 + q * 8;
            qn0 = *(const float4*)qr;        qn1 = *(const float4*)(qr + 4);
            qn2 = *(const float4*)(qr + 32); qn3 = *(const float4*)(qr + 36);
            en0 = *(const float4*)ar;        en1 = *(const float4*)(ar + 4);
            en2 = *(const float4*)(ar + 32); en3 = *(const float4*)(ar + 36);
#pragma unroll
            for (int j = 0; j < 5; ++j) {
                int ch = j * 4 + q;
                int node = ch < 10 ? siA : diA;
                int chunk = ch < 10 ? ch : ch - 10;
                GL16((const char*)he + (size_t)node * 160 + chunk * 16, sbuf + j * 1024);
            }
            int eC = min(T + 3 * NW, ntiles - 1) * 16 + c;
            siC = src_i[eC]; diC = dst_i[eC];
            asm volatile("s_waitcnt vmcnt(15)" ::: "memory");
        } else {
            qn0 = qc0; qn1 = qc1; qn2 = qc2; qn3 = qc3;
            en0 = ec0; en1 = ec1; en2 = ec2; en3 = ec3;
            asm volatile("s_waitcnt vmcnt(0)" ::: "memory");
        }
        __builtin_amdgcn_sched_barrier(0);

        // ---- compute tile T ----
        f32x4 acc0 = {}, acc1 = {}, acc2 = {}, acc3 = {};
        const char* wbase = smem + (size_t)l * 16;
#define BF(ct, ks) (*(const bf16x8*)(wbase + (ct) * 9216 + (ks) * 1024))
#define HEF(pl) (*(const bf16x8*)(cbuf + (pl) * 256 + c * 16))
#define KST(ks, A)                                                                 \
        {                                                                          \
            bf16x8 a_ = (A);                                                       \
            acc0 = __builtin_amdgcn_mfma_f32_16x16x32_bf16(a_, BF(0, ks), acc0, 0, 0, 0); \
            acc1 = __builtin_amdgcn_mfma_f32_16x16x32_bf16(a_, BF(1, ks), acc1, 0, 0, 0); \
            acc2 = __builtin_amdgcn_mfma_f32_16x16x32_bf16(a_, BF(2, ks), acc2, 0, 0, 0); \
            acc3 = __builtin_amdgcn_mfma_f32_16x16x32_bf16(a_, BF(3, ks), acc3, 0, 0, 0); \
        }
        KST(0, cvt8v(qc0, qc1))
        KST(1, cvt8v(qc2, qc3))
        KST(2, cvt8v(ec0, ec1))
        KST(3, cvt8v(ec2, ec3))
        KST(4, HEF(q))            // hs chunks q
        KST(5, HEF(q + 4))        // hs chunks q+4
        KST(6, HEF(q + 8))        // q<2: hs 8,9 ; q>=2: hd 0,1 (planes contiguous)
        KST(7, HEF(q + 12))       // hd chunks 2..5
        KST(8, HEF(q + 16))       // hd chunks 6..9
#undef KST
#undef HEF
#undef BF

        float pr[4];
#pragma unroll
        for (int r = 0; r < 4; ++r) {
            float h0 = fmaxf(acc0[r] + b1v[0], 0.f);
            float h1 = fmaxf(acc1[r] + b1v[1], 0.f);
            float h2 = fmaxf(acc2[r] + b1v[2], 0.f);
            float h3 = fmaxf(acc3[r] + b1v[3], 0.f);
            float p = fmaf(h0, w2v[0], fmaf(h1, w2v[1], fmaf(h2, w2v[2], h3 * w2v[3])));
            p += __shfl_xor(p, 1);
            p += __shfl_xor(p, 2);
            p += __shfl_xor(p, 4);
            p += __shfl_xor(p, 8);
            pr[r] = p;
        }
        if (c == 0) {
            *(float4*)&out[T * 16 + q * 4] =
                make_float4(pr[0] + bb, pr[1] + bb, pr[2] + bb, pr[3] + bb);
        }

        qc0 = qn0; qc1 = qn1; qc2 = qn2; qc3 = qn3;
        ec0 = en0; ec1 = en1; ec2 = en2; ec3 = en3;
        siA = siB; diA = diB; siB = siC; diB = diC;
        T = Tn; cur ^= 1;
    }
}

// ---------------------------------------------------------------------------
// Launch
// ---------------------------------------------------------------------------

extern "C" void kernel_launch(void* const* d_in, const int* in_sizes, int n_in,
                              void* d_out, int out_size, void* d_ws, size_t ws_size,
                              hipStream_t stream)
{
    const float* x         = (const float*)d_in[0];
    const int*   eidx      = (const int*)  d_in[1];
    const float* edge_attr = (const float*)d_in[2];
    const float* topic     = (const float*)d_in[3];
    const float* q_emb     = (const float*)d_in[4];
    const float* nte       = (const float*)d_in[5];
    const float* W1        = (const float*)d_in[6];
    const float* b1        = (const float*)d_in[7];
    const float* W2        = (const float*)d_in[8];
    const float* b2        = (const float*)d_in[9];
    float* out = (float*)d_out;

    const int E = out_size;             // 500000
    const int N = in_sizes[0] / 64;     // 50000

    char* ws = (char*)d_ws;
    int* flag  = (int*)ws;
    int* src_i = (int*)(ws + 16);
    int* dst_i = src_i + E;
    int* off_f = dst_i + E;
    int* off_r = off_f + N;
    float* fblk = (float*)(off_r + N);
    float* f1 = fblk;
    float* f2 = fblk + 2 * (size_t)N;
    float* r1 = fblk + 4 * (size_t)N;
    float* r2 = fblk + 6 * (size_t)N;
    int* cnt_dst = (int*)f1;            // dead before f1 is written
    int* cnt_src = cnt_dst + N;
    char* heblk = (char*)(fblk + 8 * (size_t)N);
    unsigned short* pos_f = (unsigned short*)heblk;          // dead before he is written
    unsigned short* pos_r = pos_f + E;
    int* csr_f = (int*)(pos_r + E);
    int* csr_r = csr_f + E;
    unsigned short* he = (unsigned short*)heblk;
    size_t he_bytes = (size_t)N * 160;
    size_t trans_bytes = (size_t)E * 12;
    size_t heblk_bytes = he_bytes > trans_bytes ? he_bytes : trans_bytes;
    unsigned short* W1T = (unsigned short*)(heblk + heblk_bytes);

    size_t needed = 16 + (size_t)8 * E + (size_t)8 * N + (size_t)32 * N + heblk_bytes + 64 * 288 * 2;
    if (ws_size < needed) return;

    hipMemsetAsync(flag, 0, 16, stream);
    hipMemsetAsync(cnt_dst, 0, (size_t)8 * N, stream);   // both cnt arrays

    const int gE = (E + 255) / 256;
    const int gN = (N + 255) / 256;
    const int gN2 = (2 * N + 255) / 256;

    k_detect <<<gE, 256, 0, stream>>>(eidx, E, flag);
    k_convert<<<gE, 256, 0, stream>>>(eidx, E, flag, src_i, dst_i,
                                      cnt_dst, cnt_src, pos_f, pos_r);
    k_scan   <<<2, 1024, 0, stream>>>(cnt_dst, cnt_src, off_f, off_r, N);
    k_fill   <<<gE, 256, 0, stream>>>(src_i, dst_i, pos_f, pos_r, off_f, off_r,
                                      csr_f, csr_r, E);
    k_round  <<<gN2, 256, 0, stream>>>(off_f, csr_f, off_r, csr_r, topic, topic, f1, r1, N, E);
    k_round  <<<gN2, 256, 0, stream>>>(off_f, csr_f, off_r, csr_r, f1, r1, f2, r2, N, E);
    k_build  <<<gN, 256, 0, stream>>>(x, topic, nte, f1, f2, r1, r2, he, N);
    k_w1t    <<<(64 * 288 + 255) / 256, 256, 0, stream>>>(W1, W1T);

    k_gemm<<<512, 256, 0, stream>>>(q_emb, edge_attr, he, W1T,
                                    src_i, dst_i, b1, W2, b2, out, E);
}